// Round 1
// baseline (700.054 us; speedup 1.0000x reference)
//
#include <hip/hip_runtime.h>

typedef unsigned short ushort_t;
typedef __attribute__((ext_vector_type(8))) short short8;
typedef __attribute__((ext_vector_type(4))) float f32x4;

// ---------- helpers ----------

__device__ __forceinline__ ushort_t f2bf(float f) {
    unsigned u = __builtin_bit_cast(unsigned, f);
    u += 0x7fffu + ((u >> 16) & 1u);   // round-to-nearest-even
    return (ushort_t)(u >> 16);
}

__device__ __forceinline__ void gld16(const ushort_t* g, ushort_t* lds) {
    // async global->LDS, 16B per lane; lds base must be wave-uniform,
    // lane i lands at base + i*16.
    __builtin_amdgcn_global_load_lds(
        (const __attribute__((address_space(1))) unsigned int*)g,
        (__attribute__((address_space(3))) unsigned int*)lds, 16, 0, 0);
}

// ---------- K1: fp32 -> bf16 conversion (grid-stride, float4 in / ushort4 out) ----------

__global__ __launch_bounds__(256) void k_cvt(const float* __restrict__ in,
                                             ushort_t* __restrict__ outp, int n4) {
    int i = blockIdx.x * blockDim.x + threadIdx.x;
    int stride = gridDim.x * blockDim.x;
    for (; i < n4; i += stride) {
        float4 v = ((const float4*)in)[i];
        ushort4 o;
        o.x = f2bf(v.x); o.y = f2bf(v.y); o.z = f2bf(v.z); o.w = f2bf(v.w);
        ((ushort4*)outp)[i] = o;
    }
}

// ---------- K0: dproj[b,a] = dot(dh[b,:], Wdec[a,:]) + bdec[a] + benc[a] ----------
// one wave per (b,a); 8192 blocks x 4 waves = 32768 pairs

__global__ __launch_bounds__(256) void k_dproj(const float* __restrict__ dh,
                                               const float* __restrict__ Wd,
                                               const float* __restrict__ bd,
                                               const float* __restrict__ be,
                                               float* __restrict__ dproj) {
    int wid = blockIdx.x * 4 + (threadIdx.x >> 6);
    int lane = threadIdx.x & 63;
    int a = wid & 1023, b = wid >> 10;
    const float4* x = (const float4*)(dh + (size_t)b * 1024);
    const float4* wrow = (const float4*)(Wd + (size_t)a * 1024);
    float s = 0.f;
#pragma unroll
    for (int it = 0; it < 4; ++it) {
        int c = it * 64 + lane;
        float4 xv = x[c], wv = wrow[c];
        s += xv.x * wv.x + xv.y * wv.y + xv.z * wv.z + xv.w * wv.w;
    }
#pragma unroll
    for (int o = 1; o < 64; o <<= 1) s += __shfl_xor(s, o, 64);
    if (lane == 0) dproj[b * 1024 + a] = s + bd[a] + be[a];
}

// ---------- K2: fused GEMM + tanh + W_v column-reduction -> scores ----------
// C[m,a] = sum_e encB[m,e]*WencB[a,e];  scores[m] += sum_a Wv[a]*tanh(C[m,a]+dproj[b,a])
// 128x128 tile, BK=64, 16x16x32 bf16 MFMA, global_load_lds(16), XOR-swizzled LDS.

__global__ __launch_bounds__(256) void k_gemm_scores(const ushort_t* __restrict__ A,
                                                     const ushort_t* __restrict__ Bm,
                                                     const float* __restrict__ dproj,
                                                     const float* __restrict__ Wv,
                                                     float* __restrict__ scores) {
    __shared__ __align__(16) ushort_t At[128 * 64];  // 16 KB, row stride 64 bf16
    __shared__ __align__(16) ushort_t Bt[128 * 64];  // 16 KB

    const int tid = threadIdx.x;
    const int lane = tid & 63;
    const int w = tid >> 6;            // wave 0..3
    const int wm = w >> 1, wn = w & 1; // 2x2 wave grid, 64x64 per wave
    const int blkN = blockIdx.x;       // 0..7   (fastest -> A-tile sharing in cache)
    const int blkM = blockIdx.y;       // 0..511
    const long long arow0 = (long long)blkM * 128;
    const int brow0 = blkN * 128;

    // staging decomposition: per wave 4 issues, each issue = 8 rows x 64 cols (1024B)
    const int sr = lane >> 3;          // row within 8-row group
    const int sgrp = lane & 7;         // 16B slot within row
    const int c8s = sgrp ^ sr;         // swizzled source column-group (row&7 == sr)

    const int q = lane >> 4;           // quad
    const int ml = lane & 15;

    f32x4 acc[4][4];
#pragma unroll
    for (int i = 0; i < 4; ++i)
#pragma unroll
        for (int jj = 0; jj < 4; ++jj) acc[i][jj] = (f32x4){0.f, 0.f, 0.f, 0.f};

    for (int k0 = 0; k0 < 1024; k0 += 64) {
        __syncthreads();   // previous compute done before overwriting LDS
#pragma unroll
        for (int j = 0; j < 4; ++j) {
            int r = (w * 4 + j) * 8 + sr;
            const ushort_t* ga = A + (arow0 + r) * 1024 + k0 + c8s * 8;
            gld16(ga, &At[(w * 4 + j) * 512]);
            const ushort_t* gb = Bm + (long long)(brow0 + r) * 1024 + k0 + c8s * 8;
            gld16(gb, &Bt[(w * 4 + j) * 512]);
        }
        __builtin_amdgcn_s_waitcnt(0);  // drain vmcnt (global_load_lds) before barrier
        __syncthreads();

#pragma unroll
        for (int kk = 0; kk < 2; ++kk) {  // two k-steps of 32
            const int kb = kk * 4;
            short8 af[4], bfr[4];
#pragma unroll
            for (int i = 0; i < 4; ++i) {
                int row = wm * 64 + i * 16 + ml;              // row&7 == ml&7
                int slot = (kb + q) ^ (row & 7);
                af[i] = *(const short8*)&At[row * 64 + slot * 8];
                int col = wn * 64 + i * 16 + ml;
                int slotb = (kb + q) ^ (col & 7);
                bfr[i] = *(const short8*)&Bt[col * 64 + slotb * 8];
            }
#pragma unroll
            for (int i = 0; i < 4; ++i)
#pragma unroll
                for (int jj = 0; jj < 4; ++jj)
                    acc[i][jj] = __builtin_amdgcn_mfma_f32_16x16x32_bf16(
                        af[i], bfr[jj], acc[i][jj], 0, 0, 0);
        }
    }

    // epilogue: scores[m] += sum over this block's 128 cols of Wv[a]*tanh(acc + dproj[b,a])
    const int bb = blkM >> 4;  // 2048/128 = 16 M-blocks per batch
#pragma unroll
    for (int i = 0; i < 4; ++i) {
        float rs[4] = {0.f, 0.f, 0.f, 0.f};
#pragma unroll
        for (int jj = 0; jj < 4; ++jj) {
            int a = blkN * 128 + wn * 64 + jj * 16 + ml;
            float dp = dproj[bb * 1024 + a];
            float wv = Wv[a];
            f32x4 v = acc[i][jj];
            rs[0] += wv * tanhf(v.x + dp);
            rs[1] += wv * tanhf(v.y + dp);
            rs[2] += wv * tanhf(v.z + dp);
            rs[3] += wv * tanhf(v.w + dp);
        }
#pragma unroll
        for (int r = 0; r < 4; ++r)
#pragma unroll
            for (int o = 1; o < 16; o <<= 1) rs[r] += __shfl_xor(rs[r], o, 64);
        if (ml == 0) {
            long long m0 = arow0 + wm * 64 + i * 16 + q * 4;
            atomicAdd(&scores[m0 + 0], rs[0]);
            atomicAdd(&scores[m0 + 1], rs[1]);
            atomicAdd(&scores[m0 + 2], rs[2]);
            atomicAdd(&scores[m0 + 3], rs[3]);
        }
    }
}

// ---------- K3: softmax over S per batch; writes alpha to out[32768+...], zeroes context ----------

__global__ __launch_bounds__(256) void k_softmax(const float* __restrict__ scores,
                                                 float* __restrict__ out) {
    const int b = blockIdx.x, t = threadIdx.x;
    const int lane = t & 63, w = t >> 6;
    __shared__ float red[4];
    float v[8];
#pragma unroll
    for (int j = 0; j < 8; ++j) v[j] = scores[b * 2048 + j * 256 + t];
    float mx = v[0];
#pragma unroll
    for (int j = 1; j < 8; ++j) mx = fmaxf(mx, v[j]);
#pragma unroll
    for (int o = 1; o < 64; o <<= 1) mx = fmaxf(mx, __shfl_xor(mx, o, 64));
    if (lane == 0) red[w] = mx;
    __syncthreads();
    mx = fmaxf(fmaxf(red[0], red[1]), fmaxf(red[2], red[3]));
    float s = 0.f;
#pragma unroll
    for (int j = 0; j < 8; ++j) { v[j] = __expf(v[j] - mx); s += v[j]; }
#pragma unroll
    for (int o = 1; o < 64; o <<= 1) s += __shfl_xor(s, o, 64);
    __syncthreads();
    if (lane == 0) red[w] = s;
    __syncthreads();
    s = red[0] + red[1] + red[2] + red[3];
    float inv = 1.0f / s;
#pragma unroll
    for (int j = 0; j < 8; ++j) out[32768 + b * 2048 + j * 256 + t] = v[j] * inv;
    // zero the context region this batch owns (poisoned 0xAA; K4 atomically accumulates)
    for (int j = t; j < 1024; j += 256) out[b * 1024 + j] = 0.f;
}

// ---------- K4: context[b,e] = sum_s alpha[b,s] * enc[b,s,e] ----------
// grid (32 batches, 16 s-chunks of 128); float4 per thread covers E=1024.

__global__ __launch_bounds__(256) void k_context(const float* __restrict__ enc,
                                                 const float* __restrict__ alpha_src,
                                                 float* __restrict__ out) {
    const int b = blockIdx.x, sc = blockIdx.y, t = threadIdx.x;
    __shared__ float al[128];
    if (t < 128) al[t] = alpha_src[32768 + b * 2048 + sc * 128 + t];
    __syncthreads();
    const float4* ep = (const float4*)(enc + ((size_t)b * 2048 + (size_t)sc * 128) * 1024);
    float ax = 0.f, ay = 0.f, az = 0.f, aw = 0.f;
    for (int s = 0; s < 128; ++s) {
        float4 ev = ep[s * 256 + t];
        float a = al[s];
        ax += a * ev.x; ay += a * ev.y; az += a * ev.z; aw += a * ev.w;
    }
    float* dst = out + b * 1024 + t * 4;
    atomicAdd(dst + 0, ax);
    atomicAdd(dst + 1, ay);
    atomicAdd(dst + 2, az);
    atomicAdd(dst + 3, aw);
}

// ---------- launch ----------

extern "C" void kernel_launch(void* const* d_in, const int* in_sizes, int n_in,
                              void* d_out, int out_size, void* d_ws, size_t ws_size,
                              hipStream_t stream) {
    const float* enc  = (const float*)d_in[0];  // [32,2048,1024]
    const float* dh   = (const float*)d_in[1];  // [32,1024]
    const float* Wenc = (const float*)d_in[2];  // [1024,1024]
    const float* benc = (const float*)d_in[3];  // [1024]
    const float* Wdec = (const float*)d_in[4];  // [1024,1024]
    const float* bdec = (const float*)d_in[5];  // [1024]
    const float* Wv   = (const float*)d_in[6];  // [1024]
    // d_in[7] (b_v) cancels in softmax -> unused
    float* out = (float*)d_out;                 // [32*1024 context | 32*2048 alpha]

    char* ws = (char*)d_ws;
    ushort_t* encB  = (ushort_t*)ws;                              // 128 MiB
    ushort_t* wencB = (ushort_t*)(ws + 134217728ull);             // 2 MiB
    float* dproj    = (float*)(ws + 134217728ull + 2097152ull);   // 128 KiB
    float* scores   = (float*)(ws + 134217728ull + 2097152ull + 131072ull); // 256 KiB

    hipMemsetAsync(scores, 0, 65536 * sizeof(float), stream);
    k_cvt<<<8192, 256, 0, stream>>>(enc, encB, 16777216);
    k_cvt<<<1024, 256, 0, stream>>>(Wenc, wencB, 262144);
    k_dproj<<<8192, 256, 0, stream>>>(dh, Wdec, bdec, benc, dproj);
    k_gemm_scores<<<dim3(8, 512), 256, 0, stream>>>(encB, wencB, dproj, Wv, scores);
    k_softmax<<<32, 256, 0, stream>>>(scores, out);
    k_context<<<dim3(32, 16), 256, 0, stream>>>(enc, out, out);
}

// Round 2
// 633.408 us; speedup vs baseline: 1.1052x; 1.1052x over previous
//
#include <hip/hip_runtime.h>

typedef unsigned short ushort_t;
typedef __attribute__((ext_vector_type(8))) short short8;
typedef __attribute__((ext_vector_type(4))) float f32x4;

// ---------- helpers ----------

__device__ __forceinline__ ushort_t f2bf(float f) {
    unsigned u = __builtin_bit_cast(unsigned, f);
    u += 0x7fffu + ((u >> 16) & 1u);   // round-to-nearest-even
    return (ushort_t)(u >> 16);
}

__device__ __forceinline__ float tanh_fast(float x) {
    // tanh(x) = 1 - 2/(exp(2x)+1).  exp(inf)->inf -> 1; exp(-inf)->0 -> -1.
    // v_mul + v_exp + v_add + v_rcp + v_fma  (~1e-6 abs err, << bf16 noise)
    float e = __expf(2.0f * x);
    float r = __builtin_amdgcn_rcpf(e + 1.0f);
    return __builtin_fmaf(-2.0f, r, 1.0f);
}

__device__ __forceinline__ void gld16(const ushort_t* g, ushort_t* lds) {
    // async global->LDS, 16B per lane; lds base wave-uniform, lane i -> base + i*16
    __builtin_amdgcn_global_load_lds(
        (const __attribute__((address_space(1))) unsigned int*)g,
        (__attribute__((address_space(3))) unsigned int*)lds, 16, 0, 0);
}

// ---------- K1: prep — enc fp32->bf16, Wenc fp32->bf16, zero scores (one dispatch) ----------

__global__ __launch_bounds__(256) void k_prep(const float* __restrict__ enc,
                                              const float* __restrict__ Wenc,
                                              ushort_t* __restrict__ encB,
                                              ushort_t* __restrict__ wencB,
                                              float4* __restrict__ scores4) {
    int i = blockIdx.x * 256 + threadIdx.x;
    const int stride = gridDim.x * 256;
    for (; i < 17055744; i += stride) {
        if (i < 16777216) {                       // enc: 16.7M float4
            float4 v = ((const float4*)enc)[i];
            ushort4 o;
            o.x = f2bf(v.x); o.y = f2bf(v.y); o.z = f2bf(v.z); o.w = f2bf(v.w);
            ((ushort4*)encB)[i] = o;
        } else if (i < 17039360) {                // Wenc: 262144 float4
            int j = i - 16777216;
            float4 v = ((const float4*)Wenc)[j];
            ushort4 o;
            o.x = f2bf(v.x); o.y = f2bf(v.y); o.z = f2bf(v.z); o.w = f2bf(v.w);
            ((ushort4*)wencB)[j] = o;
        } else {                                  // scores: 16384 float4 of zeros
            scores4[i - 17039360] = (float4){0.f, 0.f, 0.f, 0.f};
        }
    }
}

// ---------- K0: dproj[b,a] = dot(dh[b,:], Wdec[a,:]) + bdec[a] + benc[a] ----------

__global__ __launch_bounds__(256) void k_dproj(const float* __restrict__ dh,
                                               const float* __restrict__ Wd,
                                               const float* __restrict__ bd,
                                               const float* __restrict__ be,
                                               float* __restrict__ dproj) {
    int wid = blockIdx.x * 4 + (threadIdx.x >> 6);
    int lane = threadIdx.x & 63;
    int a = wid & 1023, b = wid >> 10;
    const float4* x = (const float4*)(dh + (size_t)b * 1024);
    const float4* wrow = (const float4*)(Wd + (size_t)a * 1024);
    float s = 0.f;
#pragma unroll
    for (int it = 0; it < 4; ++it) {
        int c = it * 64 + lane;
        float4 xv = x[c], wv = wrow[c];
        s += xv.x * wv.x + xv.y * wv.y + xv.z * wv.z + xv.w * wv.w;
    }
#pragma unroll
    for (int o = 1; o < 64; o <<= 1) s += __shfl_xor(s, o, 64);
    if (lane == 0) dproj[b * 1024 + a] = s + bd[a] + be[a];
}

// ---------- K2: fused GEMM + tanh + W_v column-reduction -> scores ----------
// 128x128 tile, BK=64, 16x16x32 bf16 MFMA, global_load_lds(16), XOR-swizzled LDS.
// Linear grid with XCD-aware decode: the 8 blkN sharers of an A-tile land on ONE XCD.

__global__ __launch_bounds__(256) void k_gemm_scores(const ushort_t* __restrict__ A,
                                                     const ushort_t* __restrict__ Bm,
                                                     const float* __restrict__ dproj,
                                                     const float* __restrict__ Wv,
                                                     float* __restrict__ scores) {
    __shared__ __align__(16) ushort_t At[128 * 64];  // 16 KB
    __shared__ __align__(16) ushort_t Bt[128 * 64];  // 16 KB

    const int tid = threadIdx.x;
    const int lane = tid & 63;
    const int w = tid >> 6;            // wave 0..3
    const int wm = w >> 1, wn = w & 1; // 2x2 wave grid, 64x64 per wave

    // XCD swizzle: blk&7 ~ XCD id (round-robin dispatch); pin blkM's 8 N-sharers to it
    const int blk = blockIdx.x;        // 0..4095
    const int q2 = blk >> 3;           // 0..511
    const int blkN = q2 & 7;           // 0..7
    const int blkM = (blk & 7) + ((q2 >> 3) << 3);  // 0..511
    const long long arow0 = (long long)blkM * 128;
    const int brow0 = blkN * 128;

    // staging: per wave 4 issues/matrix, each = 8 rows x 64 cols (1KB)
    const int sr = lane >> 3;          // row within 8-row group
    const int sgrp = lane & 7;         // 16B slot within row
    const int c8s = sgrp ^ sr;         // XOR-swizzled source column-group

    const int q = lane >> 4;           // quad
    const int ml = lane & 15;

    const ushort_t* ga = A + (arow0 + w * 32 + sr) * 1024 + c8s * 8;
    const ushort_t* gb = Bm + (long long)(brow0 + w * 32 + sr) * 1024 + c8s * 8;

    f32x4 acc[4][4];
#pragma unroll
    for (int i = 0; i < 4; ++i)
#pragma unroll
        for (int jj = 0; jj < 4; ++jj) acc[i][jj] = (f32x4){0.f, 0.f, 0.f, 0.f};

    for (int k0 = 0; k0 < 1024; k0 += 64) {
        __syncthreads();   // previous compute done before overwriting LDS
#pragma unroll
        for (int j = 0; j < 4; ++j) {
            gld16(ga + j * 8192, &At[(w * 4 + j) * 512]);   // j*8 rows ahead
            gld16(gb + j * 8192, &Bt[(w * 4 + j) * 512]);
        }
        ga += 64; gb += 64;
        __builtin_amdgcn_s_waitcnt(0);  // drain vmcnt before barrier
        __syncthreads();

#pragma unroll
        for (int kk = 0; kk < 2; ++kk) {  // two k-steps of 32
            const int kb = kk * 4;
            short8 af[4], bfr[4];
#pragma unroll
            for (int i = 0; i < 4; ++i) {
                int row = wm * 64 + i * 16 + ml;
                int slot = (kb + q) ^ (row & 7);
                af[i] = *(const short8*)&At[row * 64 + slot * 8];
                int col = wn * 64 + i * 16 + ml;
                int slotb = (kb + q) ^ (col & 7);
                bfr[i] = *(const short8*)&Bt[col * 64 + slotb * 8];
            }
#pragma unroll
            for (int i = 0; i < 4; ++i)
#pragma unroll
                for (int jj = 0; jj < 4; ++jj)
                    acc[i][jj] = __builtin_amdgcn_mfma_f32_16x16x32_bf16(
                        af[i], bfr[jj], acc[i][jj], 0, 0, 0);
        }
    }

    // epilogue: scores[m] += sum_a Wv[a]*tanh(acc + dproj[b,a]) over this block's 128 cols
    const int bb = blkM >> 4;  // 16 M-blocks per batch
#pragma unroll
    for (int i = 0; i < 4; ++i) {
        float rs[4] = {0.f, 0.f, 0.f, 0.f};
#pragma unroll
        for (int jj = 0; jj < 4; ++jj) {
            int a = blkN * 128 + wn * 64 + jj * 16 + ml;
            float dp = dproj[bb * 1024 + a];
            float wv = Wv[a];
            f32x4 v = acc[i][jj];
            rs[0] += wv * tanh_fast(v.x + dp);
            rs[1] += wv * tanh_fast(v.y + dp);
            rs[2] += wv * tanh_fast(v.z + dp);
            rs[3] += wv * tanh_fast(v.w + dp);
        }
#pragma unroll
        for (int r = 0; r < 4; ++r)
#pragma unroll
            for (int o = 1; o < 16; o <<= 1) rs[r] += __shfl_xor(rs[r], o, 64);
        if (ml == 0) {
            long long m0 = arow0 + wm * 64 + i * 16 + q * 4;
            atomicAdd(&scores[m0 + 0], rs[0]);
            atomicAdd(&scores[m0 + 1], rs[1]);
            atomicAdd(&scores[m0 + 2], rs[2]);
            atomicAdd(&scores[m0 + 3], rs[3]);
        }
    }
}

// ---------- K3: softmax over S per batch; writes alpha to out[32768+...] ----------

__global__ __launch_bounds__(256) void k_softmax(const float* __restrict__ scores,
                                                 float* __restrict__ out) {
    const int b = blockIdx.x, t = threadIdx.x;
    const int lane = t & 63, w = t >> 6;
    __shared__ float red[4];
    float v[8];
#pragma unroll
    for (int j = 0; j < 8; ++j) v[j] = scores[b * 2048 + j * 256 + t];
    float mx = v[0];
#pragma unroll
    for (int j = 1; j < 8; ++j) mx = fmaxf(mx, v[j]);
#pragma unroll
    for (int o = 1; o < 64; o <<= 1) mx = fmaxf(mx, __shfl_xor(mx, o, 64));
    if (lane == 0) red[w] = mx;
    __syncthreads();
    mx = fmaxf(fmaxf(red[0], red[1]), fmaxf(red[2], red[3]));
    float s = 0.f;
#pragma unroll
    for (int j = 0; j < 8; ++j) { v[j] = __expf(v[j] - mx); s += v[j]; }
#pragma unroll
    for (int o = 1; o < 64; o <<= 1) s += __shfl_xor(s, o, 64);
    __syncthreads();
    if (lane == 0) red[w] = s;
    __syncthreads();
    s = red[0] + red[1] + red[2] + red[3];
    float inv = 1.0f / s;
#pragma unroll
    for (int j = 0; j < 8; ++j) out[32768 + b * 2048 + j * 256 + t] = v[j] * inv;
}

// ---------- K4: context[b,e] = sum_s alpha[b,s]*enc[b,s,e] — atomic-free ----------
// grid (32 b, 8 e-chunks of 128 floats); 256 thr = 32 f4-lanes x 8 s-groups of 256.

__global__ __launch_bounds__(256) void k_context(const float* __restrict__ enc,
                                                 const float* __restrict__ alpha,
                                                 float* __restrict__ out) {
    const int b = blockIdx.x, ec = blockIdx.y, t = threadIdx.x;
    const int l = t & 31, g = t >> 5;
    __shared__ float al[2048];
    __shared__ f32x4 part[8][33];
#pragma unroll
    for (int j = 0; j < 8; ++j) al[j * 256 + t] = alpha[b * 2048 + j * 256 + t];
    __syncthreads();
    const float4* ep = (const float4*)enc + (size_t)b * 2048 * 256 + ec * 32 + l;
    const float* ag = &al[g * 256];
    f32x4 acc = (f32x4){0.f, 0.f, 0.f, 0.f};
#pragma unroll 8
    for (int s = 0; s < 256; ++s) {
        float4 ev = ep[(size_t)(g * 256 + s) * 256];
        float a = ag[s];
        acc.x += a * ev.x; acc.y += a * ev.y; acc.z += a * ev.z; acc.w += a * ev.w;
    }
    part[g][l] = acc;
    __syncthreads();
    if (t < 32) {
        f32x4 s = part[0][t];
#pragma unroll
        for (int gg = 1; gg < 8; ++gg) {
            f32x4 p = part[gg][t];
            s.x += p.x; s.y += p.y; s.z += p.z; s.w += p.w;
        }
        float4 o; o.x = s.x; o.y = s.y; o.z = s.z; o.w = s.w;
        ((float4*)(out + b * 1024 + ec * 128))[t] = o;
    }
}

// ---------- launch ----------

extern "C" void kernel_launch(void* const* d_in, const int* in_sizes, int n_in,
                              void* d_out, int out_size, void* d_ws, size_t ws_size,
                              hipStream_t stream) {
    const float* enc  = (const float*)d_in[0];  // [32,2048,1024]
    const float* dh   = (const float*)d_in[1];  // [32,1024]
    const float* Wenc = (const float*)d_in[2];  // [1024,1024]
    const float* benc = (const float*)d_in[3];  // [1024]
    const float* Wdec = (const float*)d_in[4];  // [1024,1024]
    const float* bdec = (const float*)d_in[5];  // [1024]
    const float* Wv   = (const float*)d_in[6];  // [1024]
    // d_in[7] (b_v) cancels in softmax -> unused
    float* out = (float*)d_out;                 // [32*1024 context | 32*2048 alpha]

    char* ws = (char*)d_ws;
    ushort_t* encB  = (ushort_t*)ws;                              // 128 MiB
    ushort_t* wencB = (ushort_t*)(ws + 134217728ull);             // 2 MiB
    float* dproj    = (float*)(ws + 134217728ull + 2097152ull);   // 128 KiB
    float* scores   = (float*)(ws + 134217728ull + 2097152ull + 131072ull); // 256 KiB

    k_prep<<<8192, 256, 0, stream>>>(enc, Wenc, encB, wencB, (float4*)scores);
    k_dproj<<<8192, 256, 0, stream>>>(dh, Wdec, bdec, benc, dproj);
    k_gemm_scores<<<4096, 256, 0, stream>>>(encB, wencB, dproj, Wv, scores);
    k_softmax<<<32, 256, 0, stream>>>(scores, out);
    k_context<<<dim3(32, 8), 256, 0, stream>>>(enc, out + 32768, out);
}

// Round 3
// 598.618 us; speedup vs baseline: 1.1695x; 1.0581x over previous
//
#include <hip/hip_runtime.h>

typedef unsigned short ushort_t;
typedef __attribute__((ext_vector_type(8))) short short8;
typedef __attribute__((ext_vector_type(4))) float f32x4;

// ---------- helpers ----------

__device__ __forceinline__ ushort_t f2bf(float f) {
    unsigned u = __builtin_bit_cast(unsigned, f);
    u += 0x7fffu + ((u >> 16) & 1u);   // round-to-nearest-even
    return (ushort_t)(u >> 16);
}

__device__ __forceinline__ float bf2f(ushort_t h) {
    unsigned u = ((unsigned)h) << 16;
    return __builtin_bit_cast(float, u);
}

__device__ __forceinline__ float tanh_fast(float x) {
    float e = __expf(2.0f * x);
    float r = __builtin_amdgcn_rcpf(e + 1.0f);
    return __builtin_fmaf(-2.0f, r, 1.0f);
}

__device__ __forceinline__ void gld16(const ushort_t* g, ushort_t* lds) {
    __builtin_amdgcn_global_load_lds(
        (const __attribute__((address_space(1))) unsigned int*)g,
        (__attribute__((address_space(3))) unsigned int*)lds, 16, 0, 0);
}

// s_waitcnt imm encoding (gfx9): vmcnt[3:0] | expcnt<<4 | lgkmcnt<<8 | vmcnt[5:4]<<14
#define WAITCNT_VM8 (8 | (7 << 4) | (15 << 8))   // vmcnt(8), exp/lgkm unconstrained
#define WAITCNT_VM0 (0 | (7 << 4) | (15 << 8))   // vmcnt(0)

// ---------- K_front: enc/Wenc fp32->bf16 + zero scores (blocks 0..8191)
//                     dproj = dh@Wdec^T + bdec + benc      (blocks 8192..16383)

__global__ __launch_bounds__(256) void k_front(const float* __restrict__ enc,
                                               const float* __restrict__ Wenc,
                                               const float* __restrict__ dh,
                                               const float* __restrict__ Wd,
                                               const float* __restrict__ bd,
                                               const float* __restrict__ be,
                                               ushort_t* __restrict__ encB,
                                               ushort_t* __restrict__ wencB,
                                               float* __restrict__ dproj,
                                               float4* __restrict__ scores4) {
    const int bx = blockIdx.x;
    const int t = threadIdx.x;
    if (bx < 8192) {
        int i = bx * 256 + t;
        for (; i < 17055744; i += 2097152) {
            if (i < 16777216) {                       // enc: 16.7M float4
                float4 v = ((const float4*)enc)[i];
                ushort4 o;
                o.x = f2bf(v.x); o.y = f2bf(v.y); o.z = f2bf(v.z); o.w = f2bf(v.w);
                ((ushort4*)encB)[i] = o;
            } else if (i < 17039360) {                // Wenc: 262144 float4
                int j = i - 16777216;
                float4 v = ((const float4*)Wenc)[j];
                ushort4 o;
                o.x = f2bf(v.x); o.y = f2bf(v.y); o.z = f2bf(v.z); o.w = f2bf(v.w);
                ((ushort4*)wencB)[j] = o;
            } else {                                  // scores zeros
                scores4[i - 17039360] = (float4){0.f, 0.f, 0.f, 0.f};
            }
        }
    } else {
        int wid = (bx - 8192) * 4 + (t >> 6);
        int lane = t & 63;
        int a = wid & 1023, b = wid >> 10;
        const float4* x = (const float4*)(dh + (size_t)b * 1024);
        const float4* wrow = (const float4*)(Wd + (size_t)a * 1024);
        float s = 0.f;
#pragma unroll
        for (int it = 0; it < 4; ++it) {
            int c = it * 64 + lane;
            float4 xv = x[c], wv = wrow[c];
            s += xv.x * wv.x + xv.y * wv.y + xv.z * wv.z + xv.w * wv.w;
        }
#pragma unroll
        for (int o = 1; o < 64; o <<= 1) s += __shfl_xor(s, o, 64);
        if (lane == 0) dproj[b * 1024 + a] = s + bd[a] + be[a];
    }
}

// ---------- K2: fused GEMM + tanh + W_v reduction -> scores ----------
// 128x128 tile, BK=64, double-buffered LDS (2x32KB), raw s_barrier + vmcnt(8)
// so next-tile global_load_lds stays in flight across the barrier.

__global__ __launch_bounds__(256, 2) void k_gemm_scores(const ushort_t* __restrict__ A,
                                                        const ushort_t* __restrict__ Bm,
                                                        const float* __restrict__ dproj,
                                                        const float* __restrict__ Wv,
                                                        float* __restrict__ scores) {
    __shared__ __align__(16) ushort_t At[2][8192];  // 2 x 16 KB
    __shared__ __align__(16) ushort_t Bt[2][8192];  // 2 x 16 KB

    const int tid = threadIdx.x;
    const int lane = tid & 63;
    const int w = tid >> 6;
    const int wm = w >> 1, wn = w & 1;

    // XCD swizzle: blk&7 ~ XCD; pin the 8 N-sharers of an A-tile to one XCD
    const int blk = blockIdx.x;
    const int q2 = blk >> 3;
    const int blkN = q2 & 7;
    const int blkM = (blk & 7) + ((q2 >> 3) << 3);
    const long long arow0 = (long long)blkM * 128;
    const int brow0 = blkN * 128;

    const int sr = lane >> 3;
    const int sgrp = lane & 7;
    const int c8s = sgrp ^ sr;          // XOR-swizzled source column-group

    const int q = lane >> 4;
    const int ml = lane & 15;

    const ushort_t* ga = A + (arow0 + w * 32 + sr) * 1024 + c8s * 8;
    const ushort_t* gb = Bm + (long long)(brow0 + w * 32 + sr) * 1024 + c8s * 8;

    f32x4 acc[4][4];
#pragma unroll
    for (int i = 0; i < 4; ++i)
#pragma unroll
        for (int jj = 0; jj < 4; ++jj) acc[i][jj] = (f32x4){0.f, 0.f, 0.f, 0.f};

    // prologue: stage tile 0 into buffer 0
#pragma unroll
    for (int j = 0; j < 4; ++j) {
        gld16(ga + j * 8192, &At[0][(w * 4 + j) * 512]);
        gld16(gb + j * 8192, &Bt[0][(w * 4 + j) * 512]);
    }

    for (int it = 0; it < 16; ++it) {
        const int cur = it & 1;
        if (it < 15) {
            const ushort_t* ga2 = ga + (it + 1) * 64;
            const ushort_t* gb2 = gb + (it + 1) * 64;
#pragma unroll
            for (int j = 0; j < 4; ++j) {
                gld16(ga2 + j * 8192, &At[cur ^ 1][(w * 4 + j) * 512]);
                gld16(gb2 + j * 8192, &Bt[cur ^ 1][(w * 4 + j) * 512]);
            }
            __builtin_amdgcn_s_waitcnt(WAITCNT_VM8);  // drain cur's 8, keep next 8 in flight
        } else {
            __builtin_amdgcn_s_waitcnt(WAITCNT_VM0);
        }
        __atomic_signal_fence(__ATOMIC_ACQ_REL);
        __builtin_amdgcn_s_barrier();                 // raw: no vmcnt(0) drain
        __atomic_signal_fence(__ATOMIC_ACQ_REL);

#pragma unroll
        for (int kk = 0; kk < 2; ++kk) {
            const int kb = kk * 4;
            short8 af[4], bfr[4];
#pragma unroll
            for (int i = 0; i < 4; ++i) {
                int row = wm * 64 + i * 16 + ml;
                int slot = (kb + q) ^ (row & 7);
                af[i] = *(const short8*)&At[cur][row * 64 + slot * 8];
                int col = wn * 64 + i * 16 + ml;
                int slotb = (kb + q) ^ (col & 7);
                bfr[i] = *(const short8*)&Bt[cur][col * 64 + slotb * 8];
            }
#pragma unroll
            for (int i = 0; i < 4; ++i)
#pragma unroll
                for (int jj = 0; jj < 4; ++jj)
                    acc[i][jj] = __builtin_amdgcn_mfma_f32_16x16x32_bf16(
                        af[i], bfr[jj], acc[i][jj], 0, 0, 0);
        }
        __atomic_signal_fence(__ATOMIC_ACQ_REL);
        __builtin_amdgcn_s_barrier();                 // all reads of cur done before overwrite
        __atomic_signal_fence(__ATOMIC_ACQ_REL);
    }

    // epilogue
    const int bb = blkM >> 4;
#pragma unroll
    for (int i = 0; i < 4; ++i) {
        float rs[4] = {0.f, 0.f, 0.f, 0.f};
#pragma unroll
        for (int jj = 0; jj < 4; ++jj) {
            int a = blkN * 128 + wn * 64 + jj * 16 + ml;
            float dp = dproj[bb * 1024 + a];
            float wv = Wv[a];
            f32x4 v = acc[i][jj];
            rs[0] += wv * tanh_fast(v.x + dp);
            rs[1] += wv * tanh_fast(v.y + dp);
            rs[2] += wv * tanh_fast(v.z + dp);
            rs[3] += wv * tanh_fast(v.w + dp);
        }
#pragma unroll
        for (int r = 0; r < 4; ++r)
#pragma unroll
            for (int o = 1; o < 16; o <<= 1) rs[r] += __shfl_xor(rs[r], o, 64);
        if (ml == 0) {
            long long m0 = arow0 + wm * 64 + i * 16 + q * 4;
            atomicAdd(&scores[m0 + 0], rs[0]);
            atomicAdd(&scores[m0 + 1], rs[1]);
            atomicAdd(&scores[m0 + 2], rs[2]);
            atomicAdd(&scores[m0 + 3], rs[3]);
        }
    }
}

// ---------- K3: softmax; writes alpha, zeroes context region for K4's atomics ----------

__global__ __launch_bounds__(256) void k_softmax(const float* __restrict__ scores,
                                                 float* __restrict__ out) {
    const int b = blockIdx.x, t = threadIdx.x;
    const int lane = t & 63, w = t >> 6;
    __shared__ float red[4];
#pragma unroll
    for (int j = t; j < 1024; j += 256) out[b * 1024 + j] = 0.f;   // context zeros
    float v[8];
#pragma unroll
    for (int j = 0; j < 8; ++j) v[j] = scores[b * 2048 + j * 256 + t];
    float mx = v[0];
#pragma unroll
    for (int j = 1; j < 8; ++j) mx = fmaxf(mx, v[j]);
#pragma unroll
    for (int o = 1; o < 64; o <<= 1) mx = fmaxf(mx, __shfl_xor(mx, o, 64));
    if (lane == 0) red[w] = mx;
    __syncthreads();
    mx = fmaxf(fmaxf(red[0], red[1]), fmaxf(red[2], red[3]));
    float s = 0.f;
#pragma unroll
    for (int j = 0; j < 8; ++j) { v[j] = __expf(v[j] - mx); s += v[j]; }
#pragma unroll
    for (int o = 1; o < 64; o <<= 1) s += __shfl_xor(s, o, 64);
    __syncthreads();
    if (lane == 0) red[w] = s;
    __syncthreads();
    s = red[0] + red[1] + red[2] + red[3];
    float inv = 1.0f / s;
#pragma unroll
    for (int j = 0; j < 8; ++j) out[32768 + b * 2048 + j * 256 + t] = v[j] * inv;
}

// ---------- K4: context[b,e] = sum_s alpha[b,s]*encB[b,s,e] (bf16 reads) ----------
// grid (32 b, 8 e-chunks, 8 s-chunks) = 2048 blocks; atomicAdd into zeroed out.

__global__ __launch_bounds__(256) void k_context(const ushort_t* __restrict__ encB,
                                                 const float* __restrict__ alpha,
                                                 float* __restrict__ out) {
    const int b = blockIdx.x, ec = blockIdx.y, sc = blockIdx.z, t = threadIdx.x;
    const int l = t & 31, g = t >> 5;
    __shared__ float al[256];
    __shared__ f32x4 part[8][33];
    al[t] = alpha[b * 2048 + sc * 256 + t];
    __syncthreads();
    const ushort_t* ep = encB + ((size_t)(b * 2048 + sc * 256 + g * 32)) * 1024 + ec * 128 + l * 4;
    const float* ag = &al[g * 32];
    f32x4 acc = (f32x4){0.f, 0.f, 0.f, 0.f};
#pragma unroll 4
    for (int s = 0; s < 32; ++s) {
        ushort4 ev = *(const ushort4*)(ep + (size_t)s * 1024);
        float a = ag[s];
        acc.x += a * bf2f(ev.x);
        acc.y += a * bf2f(ev.y);
        acc.z += a * bf2f(ev.z);
        acc.w += a * bf2f(ev.w);
    }
    part[g][l] = acc;
    __syncthreads();
    if (t < 32) {
        f32x4 s = part[0][t];
#pragma unroll
        for (int gg = 1; gg < 8; ++gg) {
            f32x4 p = part[gg][t];
            s.x += p.x; s.y += p.y; s.z += p.z; s.w += p.w;
        }
        float* dst = out + b * 1024 + ec * 128 + t * 4;
        atomicAdd(dst + 0, s.x);
        atomicAdd(dst + 1, s.y);
        atomicAdd(dst + 2, s.z);
        atomicAdd(dst + 3, s.w);
    }
}

// ---------- launch ----------

extern "C" void kernel_launch(void* const* d_in, const int* in_sizes, int n_in,
                              void* d_out, int out_size, void* d_ws, size_t ws_size,
                              hipStream_t stream) {
    const float* enc  = (const float*)d_in[0];
    const float* dh   = (const float*)d_in[1];
    const float* Wenc = (const float*)d_in[2];
    const float* benc = (const float*)d_in[3];
    const float* Wdec = (const float*)d_in[4];
    const float* bdec = (const float*)d_in[5];
    const float* Wv   = (const float*)d_in[6];
    float* out = (float*)d_out;                 // [32*1024 context | 32*2048 alpha]

    char* ws = (char*)d_ws;
    ushort_t* encB  = (ushort_t*)ws;                              // 128 MiB
    ushort_t* wencB = (ushort_t*)(ws + 134217728ull);             // 2 MiB
    float* dproj    = (float*)(ws + 134217728ull + 2097152ull);   // 128 KiB
    float* scores   = (float*)(ws + 134217728ull + 2097152ull + 131072ull); // 256 KiB

    k_front<<<16384, 256, 0, stream>>>(enc, Wenc, dh, Wdec, bdec, benc,
                                       encB, wencB, dproj, (float4*)scores);
    k_gemm_scores<<<4096, 256, 0, stream>>>(encB, wencB, dproj, Wv, scores);
    k_softmax<<<32, 256, 0, stream>>>(scores, out);
    k_context<<<dim3(32, 8, 8), 256, 0, stream>>>(encB, out + 32768, out);
}

// Round 4
// 550.461 us; speedup vs baseline: 1.2718x; 1.0875x over previous
//
#include <hip/hip_runtime.h>

typedef unsigned short ushort_t;
typedef __attribute__((ext_vector_type(8))) short short8;
typedef __attribute__((ext_vector_type(4))) float f32x4;

// ---------- helpers ----------

__device__ __forceinline__ ushort_t f2bf(float f) {
    unsigned u = __builtin_bit_cast(unsigned, f);
    u += 0x7fffu + ((u >> 16) & 1u);   // round-to-nearest-even
    return (ushort_t)(u >> 16);
}

__device__ __forceinline__ float bf2f(ushort_t h) {
    unsigned u = ((unsigned)h) << 16;
    return __builtin_bit_cast(float, u);
}

__device__ __forceinline__ float tanh_fast(float x) {
    float e = __expf(2.0f * x);
    float r = __builtin_amdgcn_rcpf(e + 1.0f);
    return __builtin_fmaf(-2.0f, r, 1.0f);
}

__device__ __forceinline__ void gld16(const ushort_t* g, ushort_t* lds) {
    __builtin_amdgcn_global_load_lds(
        (const __attribute__((address_space(1))) unsigned int*)g,
        (__attribute__((address_space(3))) unsigned int*)lds, 16, 0, 0);
}

// ---------- K_front: enc/Wenc fp32->bf16 + zero scores (blocks 0..8191)
//                     dproj = dh@Wdec^T + bdec + benc      (blocks 8192..16383)

__global__ __launch_bounds__(256) void k_front(const float* __restrict__ enc,
                                               const float* __restrict__ Wenc,
                                               const float* __restrict__ dh,
                                               const float* __restrict__ Wd,
                                               const float* __restrict__ bd,
                                               const float* __restrict__ be,
                                               ushort_t* __restrict__ encB,
                                               ushort_t* __restrict__ wencB,
                                               float* __restrict__ dproj,
                                               float4* __restrict__ scores4) {
    const int bx = blockIdx.x;
    const int t = threadIdx.x;
    if (bx < 8192) {
        int i = bx * 256 + t;
        for (; i < 17055744; i += 2097152) {
            if (i < 16777216) {                       // enc: 16.7M float4
                float4 v = ((const float4*)enc)[i];
                ushort4 o;
                o.x = f2bf(v.x); o.y = f2bf(v.y); o.z = f2bf(v.z); o.w = f2bf(v.w);
                ((ushort4*)encB)[i] = o;
            } else if (i < 17039360) {                // Wenc: 262144 float4
                int j = i - 16777216;
                float4 v = ((const float4*)Wenc)[j];
                ushort4 o;
                o.x = f2bf(v.x); o.y = f2bf(v.y); o.z = f2bf(v.z); o.w = f2bf(v.w);
                ((ushort4*)wencB)[j] = o;
            } else {                                  // scores zeros
                scores4[i - 17039360] = (float4){0.f, 0.f, 0.f, 0.f};
            }
        }
    } else {
        int wid = (bx - 8192) * 4 + (t >> 6);
        int lane = t & 63;
        int a = wid & 1023, b = wid >> 10;
        const float4* x = (const float4*)(dh + (size_t)b * 1024);
        const float4* wrow = (const float4*)(Wd + (size_t)a * 1024);
        float s = 0.f;
#pragma unroll
        for (int it = 0; it < 4; ++it) {
            int c = it * 64 + lane;
            float4 xv = x[c], wv = wrow[c];
            s += xv.x * wv.x + xv.y * wv.y + xv.z * wv.z + xv.w * wv.w;
        }
#pragma unroll
        for (int o = 1; o < 64; o <<= 1) s += __shfl_xor(s, o, 64);
        if (lane == 0) dproj[b * 1024 + a] = s + bd[a] + be[a];
    }
}

// ---------- K2: fused GEMM + tanh + W_v reduction -> scores ----------
// 256x128 block tile (4 waves, 128x64 each), BK=64, single-buffer 48 KB LDS,
// 16x16x32 bf16 MFMA, global_load_lds(16), XOR-swizzled LDS, XCD-aware grid.
// Wave tile 128x64 -> 42.7 FLOP per LDS byte (vs 32 for 64x64).

__global__ __launch_bounds__(256, 2) void k_gemm_scores(const ushort_t* __restrict__ A,
                                                        const ushort_t* __restrict__ Bm,
                                                        const float* __restrict__ dproj,
                                                        const float* __restrict__ Wv,
                                                        float* __restrict__ scores) {
    __shared__ __align__(16) ushort_t At[256 * 64];  // 32 KB
    __shared__ __align__(16) ushort_t Bt[128 * 64];  // 16 KB

    const int tid = threadIdx.x;
    const int lane = tid & 63;
    const int w = tid >> 6;            // wave 0..3
    const int wm = w >> 1, wn = w & 1; // waves: 2 (M) x 2 (N); wave tile 128x64

    // XCD swizzle: blk&7 ~ XCD; the 8 N-sharers of an A-tile land on one XCD
    const int blk = blockIdx.x;        // 0..2047
    const int q2 = blk >> 3;           // 0..255
    const int blkN = q2 & 7;           // 0..7
    const int blkM = (blk & 7) + ((q2 >> 3) << 3);  // 0..255
    const long long arow0 = (long long)blkM * 256;
    const int brow0 = blkN * 128;

    const int sr = lane >> 3;          // row within 8-row staging group
    const int sgrp = lane & 7;         // 16B slot within row
    const int c8s = sgrp ^ sr;         // XOR-swizzled source column-group

    const int q = lane >> 4;           // quad
    const int ml = lane & 15;

    const ushort_t* ga = A + (arow0 + w * 64 + sr) * 1024 + c8s * 8;
    const ushort_t* gb = Bm + (long long)(brow0 + w * 32 + sr) * 1024 + c8s * 8;

    f32x4 acc[8][4];
#pragma unroll
    for (int i = 0; i < 8; ++i)
#pragma unroll
        for (int jj = 0; jj < 4; ++jj) acc[i][jj] = (f32x4){0.f, 0.f, 0.f, 0.f};

    for (int k0 = 0; k0 < 1024; k0 += 64) {
        __syncthreads();   // previous compute done before overwriting LDS
#pragma unroll
        for (int j = 0; j < 8; ++j)                   // A: 64 rows per wave
            gld16(ga + j * 8192, &At[(w * 8 + j) * 512]);
#pragma unroll
        for (int j = 0; j < 4; ++j)                   // B: 32 rows per wave
            gld16(gb + j * 8192, &Bt[(w * 4 + j) * 512]);
        ga += 64; gb += 64;
        __builtin_amdgcn_s_waitcnt(0);  // drain vmcnt before barrier
        __syncthreads();

#pragma unroll
        for (int kk = 0; kk < 2; ++kk) {  // two k-steps of 32
            const int kb = kk * 4;
            const int slot = (kb + q) ^ (ml & 7);     // same for A and B frags
            short8 af[8], bfr[4];
#pragma unroll
            for (int i = 0; i < 8; ++i) {
                int row = wm * 128 + i * 16 + ml;
                af[i] = *(const short8*)&At[row * 64 + slot * 8];
            }
#pragma unroll
            for (int jj = 0; jj < 4; ++jj) {
                int col = wn * 64 + jj * 16 + ml;
                bfr[jj] = *(const short8*)&Bt[col * 64 + slot * 8];
            }
#pragma unroll
            for (int i = 0; i < 8; ++i)
#pragma unroll
                for (int jj = 0; jj < 4; ++jj)
                    acc[i][jj] = __builtin_amdgcn_mfma_f32_16x16x32_bf16(
                        af[i], bfr[jj], acc[i][jj], 0, 0, 0);
        }
    }

    // epilogue: scores[m] += sum_a Wv[a]*tanh(acc + dproj[b,a]) over 128 cols
    const int bb = blkM >> 3;  // 8 M-blocks (256 rows) per batch (2048 rows)
    float dp[4], wv[4];
#pragma unroll
    for (int jj = 0; jj < 4; ++jj) {
        int a = blkN * 128 + wn * 64 + jj * 16 + ml;
        dp[jj] = dproj[bb * 1024 + a];
        wv[jj] = Wv[a];
    }
#pragma unroll
    for (int i = 0; i < 8; ++i) {
        float rs[4] = {0.f, 0.f, 0.f, 0.f};
#pragma unroll
        for (int jj = 0; jj < 4; ++jj) {
            f32x4 v = acc[i][jj];
            rs[0] += wv[jj] * tanh_fast(v.x + dp[jj]);
            rs[1] += wv[jj] * tanh_fast(v.y + dp[jj]);
            rs[2] += wv[jj] * tanh_fast(v.z + dp[jj]);
            rs[3] += wv[jj] * tanh_fast(v.w + dp[jj]);
        }
#pragma unroll
        for (int r = 0; r < 4; ++r)
#pragma unroll
            for (int o = 1; o < 16; o <<= 1) rs[r] += __shfl_xor(rs[r], o, 64);
        if (ml == 0) {
            long long m0 = arow0 + wm * 128 + i * 16 + q * 4;
            atomicAdd(&scores[m0 + 0], rs[0]);
            atomicAdd(&scores[m0 + 1], rs[1]);
            atomicAdd(&scores[m0 + 2], rs[2]);
            atomicAdd(&scores[m0 + 3], rs[3]);
        }
    }
}

// ---------- K3: softmax; writes alpha, zeroes context region for K4's atomics ----------

__global__ __launch_bounds__(256) void k_softmax(const float* __restrict__ scores,
                                                 float* __restrict__ out) {
    const int b = blockIdx.x, t = threadIdx.x;
    const int lane = t & 63, w = t >> 6;
    __shared__ float red[4];
#pragma unroll
    for (int j = t; j < 1024; j += 256) out[b * 1024 + j] = 0.f;   // context zeros
    float v[8];
#pragma unroll
    for (int j = 0; j < 8; ++j) v[j] = scores[b * 2048 + j * 256 + t];
    float mx = v[0];
#pragma unroll
    for (int j = 1; j < 8; ++j) mx = fmaxf(mx, v[j]);
#pragma unroll
    for (int o = 1; o < 64; o <<= 1) mx = fmaxf(mx, __shfl_xor(mx, o, 64));
    if (lane == 0) red[w] = mx;
    __syncthreads();
    mx = fmaxf(fmaxf(red[0], red[1]), fmaxf(red[2], red[3]));
    float s = 0.f;
#pragma unroll
    for (int j = 0; j < 8; ++j) { v[j] = __expf(v[j] - mx); s += v[j]; }
#pragma unroll
    for (int o = 1; o < 64; o <<= 1) s += __shfl_xor(s, o, 64);
    __syncthreads();
    if (lane == 0) red[w] = s;
    __syncthreads();
    s = red[0] + red[1] + red[2] + red[3];
    float inv = 1.0f / s;
#pragma unroll
    for (int j = 0; j < 8; ++j) out[32768 + b * 2048 + j * 256 + t] = v[j] * inv;
}

// ---------- K4: context[b,e] = sum_s alpha[b,s]*encB[b,s,e] (bf16 reads) ----------

__global__ __launch_bounds__(256) void k_context(const ushort_t* __restrict__ encB,
                                                 const float* __restrict__ alpha,
                                                 float* __restrict__ out) {
    const int b = blockIdx.x, ec = blockIdx.y, sc = blockIdx.z, t = threadIdx.x;
    const int l = t & 31, g = t >> 5;
    __shared__ float al[256];
    __shared__ f32x4 part[8][33];
    al[t] = alpha[b * 2048 + sc * 256 + t];
    __syncthreads();
    const ushort_t* ep = encB + ((size_t)(b * 2048 + sc * 256 + g * 32)) * 1024 + ec * 128 + l * 4;
    const float* ag = &al[g * 32];
    f32x4 acc = (f32x4){0.f, 0.f, 0.f, 0.f};
#pragma unroll 4
    for (int s = 0; s < 32; ++s) {
        ushort4 ev = *(const ushort4*)(ep + (size_t)s * 1024);
        float a = ag[s];
        acc.x += a * bf2f(ev.x);
        acc.y += a * bf2f(ev.y);
        acc.z += a * bf2f(ev.z);
        acc.w += a * bf2f(ev.w);
    }
    part[g][l] = acc;
    __syncthreads();
    if (t < 32) {
        f32x4 s = part[0][t];
#pragma unroll
        for (int gg = 1; gg < 8; ++gg) {
            f32x4 p = part[gg][t];
            s.x += p.x; s.y += p.y; s.z += p.z; s.w += p.w;
        }
        float* dst = out + b * 1024 + ec * 128 + t * 4;
        atomicAdd(dst + 0, s.x);
        atomicAdd(dst + 1, s.y);
        atomicAdd(dst + 2, s.z);
        atomicAdd(dst + 3, s.w);
    }
}

// ---------- launch ----------

extern "C" void kernel_launch(void* const* d_in, const int* in_sizes, int n_in,
                              void* d_out, int out_size, void* d_ws, size_t ws_size,
                              hipStream_t stream) {
    const float* enc  = (const float*)d_in[0];
    const float* dh   = (const float*)d_in[1];
    const float* Wenc = (const float*)d_in[2];
    const float* benc = (const float*)d_in[3];
    const float* Wdec = (const float*)d_in[4];
    const float* bdec = (const float*)d_in[5];
    const float* Wv   = (const float*)d_in[6];
    float* out = (float*)d_out;                 // [32*1024 context | 32*2048 alpha]

    char* ws = (char*)d_ws;
    ushort_t* encB  = (ushort_t*)ws;                              // 128 MiB
    ushort_t* wencB = (ushort_t*)(ws + 134217728ull);             // 2 MiB
    float* dproj    = (float*)(ws + 134217728ull + 2097152ull);   // 128 KiB
    float* scores   = (float*)(ws + 134217728ull + 2097152ull + 131072ull); // 256 KiB

    k_front<<<16384, 256, 0, stream>>>(enc, Wenc, dh, Wdec, bdec, benc,
                                       encB, wencB, dproj, (float4*)scores);
    k_gemm_scores<<<2048, 256, 0, stream>>>(encB, wencB, dproj, Wv, scores);
    k_softmax<<<32, 256, 0, stream>>>(scores, out);
    k_context<<<dim3(32, 8, 8), 256, 0, stream>>>(encB, out + 32768, out);
}